// Round 8
// baseline (219.570 us; speedup 1.0000x reference)
//
#include <hip/hip_runtime.h>
#include <hip/hip_bf16.h>
#include <math.h>

// Problem constants
#define NRES 512
#define CS 384
#define CZ 128
#define NH 12
#define CC 16
#define NQP 4
#define NPV 8
#define HC (NH*CC)        // 192
#define FTOT 1152         // 192*3 + 144*2 + 288
#define CATF 2112         // 192 + 288 + 96 + 1536
#define FSPLIT 8
#define FCHUNK 264        // 2112/8
#define W_C 0.23570226039551584f   // sqrt(2/(9*4))
#define W_L 0.5773502691896258f    // sqrt(1/3)

// ---------------- Kernel 1a: all projections as one GEMM ----------------
__global__ __launch_bounds__(384) void k_gemm(
    const float* __restrict__ s,
    const float* __restrict__ Wq, const float* __restrict__ bq,
    const float* __restrict__ Wk, const float* __restrict__ bk,
    const float* __restrict__ Wv, const float* __restrict__ bv,
    const float* __restrict__ Wqp, const float* __restrict__ bqp,
    const float* __restrict__ Wkp, const float* __restrict__ bkp,
    const float* __restrict__ Wvp, const float* __restrict__ bvp,
    float* __restrict__ p_raw)
{
    int r0 = blockIdx.x * 8;
    int f  = blockIdx.y * 384 + threadIdx.x;
    const float* W; const float* bia; int col; int stride;
    if      (f < 192) { W = Wq;  bia = bq;  col = f;       stride = 192; }
    else if (f < 384) { W = Wk;  bia = bk;  col = f - 192; stride = 192; }
    else if (f < 576) { W = Wv;  bia = bv;  col = f - 384; stride = 192; }
    else if (f < 720) { W = Wqp; bia = bqp; col = f - 576; stride = 144; }
    else if (f < 864) { W = Wkp; bia = bkp; col = f - 720; stride = 144; }
    else              { W = Wvp; bia = bvp; col = f - 864; stride = 288; }

    float acc[8];
    float b0 = bia[col];
    #pragma unroll
    for (int j = 0; j < 8; ++j) acc[j] = b0;

    const float* srow = s + (size_t)r0 * CS;
    #pragma unroll 4
    for (int i = 0; i < CS; ++i) {
        float w = W[(size_t)i * stride + col];
        #pragma unroll
        for (int j = 0; j < 8; ++j) acc[j] = fmaf(w, srow[j*CS + i], acc[j]);
    }
    #pragma unroll
    for (int j = 0; j < 8; ++j) p_raw[(size_t)(r0 + j)*FTOT + f] = acc[j];
}

// ---------------- Kernel 1b: warp + transpose layouts ----------------
__global__ __launch_bounds__(256) void k_post(
    const float* __restrict__ p_raw, const float* __restrict__ T,
    float* __restrict__ q_s, float4* __restrict__ k_t4, float4* __restrict__ v_t4,
    float* __restrict__ wq, float4* __restrict__ wk_t4, float4* __restrict__ wv_t4,
    float* __restrict__ qn, float* __restrict__ kn)
{
    int n = blockIdx.x;
    int tid = threadIdx.x;
    __shared__ float pl[FTOT];
    __shared__ float Rl[9], tl[3];
    __shared__ float wq_l[144], wk_l[144], wv_l[288];
    __shared__ float sq_part[48], sk_part[48];

    for (int idx = tid; idx < FTOT/4; idx += 256)
        *reinterpret_cast<float4*>(&pl[idx*4]) =
            *reinterpret_cast<const float4*>(&p_raw[(size_t)n*FTOT + idx*4]);
    if (tid < 9)  Rl[tid] = T[n*16 + (tid/3)*4 + (tid%3)];
    if (tid >= 16 && tid < 19) tl[tid-16] = T[n*16 + (tid-16)*4 + 3];
    __syncthreads();

    if (tid < 48) {
        int h = tid >> 2, p = tid & 3;
        float qy0 = pl[576 + 0*48 + h*4 + p], qy1 = pl[576 + 1*48 + h*4 + p], qy2 = pl[576 + 2*48 + h*4 + p];
        float ky0 = pl[720 + 0*48 + h*4 + p], ky1 = pl[720 + 1*48 + h*4 + p], ky2 = pl[720 + 2*48 + h*4 + p];
        float qs2 = 0.f, ks2 = 0.f;
        #pragma unroll
        for (int x = 0; x < 3; ++x) {
            float wqv = Rl[x*3+0]*qy0 + Rl[x*3+1]*qy1 + Rl[x*3+2]*qy2 + tl[x];
            float wkv = Rl[x*3+0]*ky0 + Rl[x*3+1]*ky1 + Rl[x*3+2]*ky2 + tl[x];
            wq_l[h*12 + p*3 + x] = wqv;
            wk_l[h*12 + p*3 + x] = wkv;
            qs2 += wqv*wqv; ks2 += wkv*wkv;
        }
        sq_part[tid] = qs2; sk_part[tid] = ks2;
    } else if (tid >= 64 && tid < 160) {
        int u = tid - 64; int h = u >> 3, p = u & 7;
        float y0 = pl[864 + 0*96 + h*8 + p], y1 = pl[864 + 1*96 + h*8 + p], y2 = pl[864 + 2*96 + h*8 + p];
        #pragma unroll
        for (int x = 0; x < 3; ++x) {
            wv_l[h*24 + p*3 + x] = Rl[x*3+0]*y0 + Rl[x*3+1]*y1 + Rl[x*3+2]*y2 + tl[x];
        }
    }
    __syncthreads();

    if (tid < 48) {
        int h = tid >> 2, c4 = tid & 3;
        float4 qv = *reinterpret_cast<const float4*>(&pl[h*16 + c4*4]);
        qv.x *= 0.25f; qv.y *= 0.25f; qv.z *= 0.25f; qv.w *= 0.25f;
        float4 kv = *reinterpret_cast<const float4*>(&pl[192 + h*16 + c4*4]);
        float4 vv = *reinterpret_cast<const float4*>(&pl[384 + h*16 + c4*4]);
        *reinterpret_cast<float4*>(&q_s[((size_t)h*NRES + n)*16 + c4*4]) = qv;
        k_t4[((size_t)h*4 + c4)*NRES + n] = kv;
        v_t4[((size_t)h*4 + c4)*NRES + n] = vv;
    } else if (tid >= 64 && tid < 100) {
        int u = tid - 64; int h = u / 3, e4 = u % 3;
        float4 kv = *reinterpret_cast<const float4*>(&wk_l[h*12 + e4*4]);
        wk_t4[((size_t)h*3 + e4)*NRES + n] = kv;
    } else if (tid >= 104 && tid < 140) {
        int u = tid - 104; int h = u / 3, e4 = u % 3;
        float4 qv = *reinterpret_cast<const float4*>(&wq_l[h*12 + e4*4]);
        *reinterpret_cast<float4*>(&wq[((size_t)h*NRES + n)*12 + e4*4]) = qv;
    } else if (tid >= 160 && tid < 232) {
        int u = tid - 160; int h = u / 6, e4 = u % 6;
        float4 vv = *reinterpret_cast<const float4*>(&wv_l[h*24 + e4*4]);
        wv_t4[((size_t)h*6 + e4)*NRES + n] = vv;
    } else if (tid >= 232 && tid < 244) {
        int h = tid - 232;
        qn[(size_t)h*NRES + n] = sq_part[h*4] + sq_part[h*4+1] + sq_part[h*4+2] + sq_part[h*4+3];
        kn[(size_t)h*NRES + n] = sk_part[h*4] + sk_part[h*4+1] + sk_part[h*4+2] + sk_part[h*4+3];
    }
}

// ---------------- Kernel 2: bias = z @ Wb + bb  -> [H][N][N] ----------------
// Quad-per-row: thread (r=tid>>2, q=tid&3); lane q reads float4 at c4=it*4+q,
// so a wave covers 16 rows x 64B contiguous (full-line transactions). Wb from
// LDS: 4 distinct addrs/wave -> 16-lane broadcasts, worst 2-way bank alias.
// Quad reduce = 2 shfl_xor per h at the end.
__global__ __launch_bounds__(256) void k_bias(
    const float* __restrict__ z, const float* __restrict__ Wb,
    const float* __restrict__ bb, float* __restrict__ bias)
{
    int j0 = blockIdx.x * 64, i = blockIdx.y;
    int tid = threadIdx.x;
    int r = tid >> 2, q = tid & 3;
    __shared__ float wbl[12*128];   // [h][c]
    __shared__ float biasl[12*64];
    __shared__ float bbl[12];

    for (int idx = tid; idx < 1536; idx += 256) {
        int h = idx >> 7, c = idx & 127;
        wbl[idx] = Wb[c*12 + h];    // consecutive idx -> consecutive LDS addr
    }
    if (tid < 12) bbl[tid] = bb[tid];
    __syncthreads();

    int j = j0 + r;
    const float4* zrow = reinterpret_cast<const float4*>(z + ((size_t)i*NRES + j)*CZ);
    float acc[12] = {0,0,0,0,0,0,0,0,0,0,0,0};
    #pragma unroll
    for (int it = 0; it < 8; ++it) {
        int c4 = it*4 + q;
        float4 zv = zrow[c4];
        #pragma unroll
        for (int h = 0; h < 12; ++h) {
            float4 wv = *reinterpret_cast<const float4*>(&wbl[h*128 + c4*4]);
            acc[h] = fmaf(zv.x, wv.x, fmaf(zv.y, wv.y, fmaf(zv.z, wv.z, fmaf(zv.w, wv.w, acc[h]))));
        }
    }
    #pragma unroll
    for (int h = 0; h < 12; ++h) {
        float v = acc[h];
        v += __shfl_xor(v, 1);
        v += __shfl_xor(v, 2);
        if (q == 0) biasl[h*64 + r] = v;
    }
    __syncthreads();

    #pragma unroll
    for (int u = 0; u < 3; ++u) {
        int idx = u*256 + tid;
        int h = idx >> 6, rr = idx & 63;
        bias[((size_t)h*NRES + i)*NRES + j0 + rr] = biasl[idx] + bbl[h];
    }
}

// ------- Kernel 3: att softmax (in-place over bias) + v_out + o_pt transform -> cat -------
__global__ __launch_bounds__(256) void k_att(
    const float* __restrict__ q_s, const float4* __restrict__ k_t4,
    const float* __restrict__ wq, const float4* __restrict__ wk_t4,
    const float* __restrict__ qn, const float* __restrict__ kn,
    const float* __restrict__ hw, const float* __restrict__ T,
    float* __restrict__ bias,       // in: bias, out: att
    const float4* __restrict__ v_t4, const float4* __restrict__ wv_t4,
    float* __restrict__ cat)
{
    int i = blockIdx.x, h = blockIdx.y;
    int tid = threadIdx.x;
    __shared__ float ql[16], wql[12];
    __shared__ float att[NRES];
    __shared__ float red[8];
    __shared__ float optl[24];
    __shared__ float sG, sQn;

    if (tid < 16) ql[tid] = q_s[((size_t)h*NRES + i)*16 + tid];
    else if (tid < 28) wql[tid-16] = wq[((size_t)h*NRES + i)*12 + (tid-16)];
    if (tid == 0) {
        sQn = qn[(size_t)h*NRES + i];
        float x = hw[h];
        float sp = (x > 20.f) ? x : log1pf(expf(x));
        sG = sp * W_C * 0.5f;
    }
    __syncthreads();
    float qn_i = sQn, gam = sG;

    float lg[2];
    #pragma unroll
    for (int m = 0; m < 2; ++m) {
        int j = tid + m*256;
        float qk = 0.f;
        #pragma unroll
        for (int c4 = 0; c4 < 4; ++c4) {
            float4 kv = k_t4[((size_t)h*4 + c4)*NRES + j];
            qk += ql[c4*4+0]*kv.x + ql[c4*4+1]*kv.y + ql[c4*4+2]*kv.z + ql[c4*4+3]*kv.w;
        }
        float dd = 0.f;
        #pragma unroll
        for (int e4 = 0; e4 < 3; ++e4) {
            float4 kv = wk_t4[((size_t)h*3 + e4)*NRES + j];
            dd += wql[e4*4+0]*kv.x + wql[e4*4+1]*kv.y + wql[e4*4+2]*kv.z + wql[e4*4+3]*kv.w;
        }
        float d2 = qn_i + kn[(size_t)h*NRES + j] - 2.f*dd;
        lg[m] = W_L * (qk + bias[((size_t)h*NRES + i)*NRES + j] - gam*d2);
    }

    int wave = tid >> 6, lane = tid & 63;
    float mx = fmaxf(lg[0], lg[1]);
    #pragma unroll
    for (int d = 32; d > 0; d >>= 1) mx = fmaxf(mx, __shfl_xor(mx, d));
    if (lane == 0) red[wave] = mx;
    __syncthreads();
    mx = fmaxf(fmaxf(red[0], red[1]), fmaxf(red[2], red[3]));
    float e0 = __expf(lg[0]-mx), e1 = __expf(lg[1]-mx);
    float sm = e0 + e1;
    #pragma unroll
    for (int d = 32; d > 0; d >>= 1) sm += __shfl_xor(sm, d);
    if (lane == 0) red[4+wave] = sm;
    __syncthreads();
    float inv = 1.f / (red[4]+red[5]+red[6]+red[7]);
    float a0 = e0*inv, a1 = e1*inv;
    att[tid] = a0; att[tid+256] = a1;
    bias[((size_t)h*NRES + i)*NRES + tid]       = a0;
    bias[((size_t)h*NRES + i)*NRES + tid + 256] = a1;
    __syncthreads();

    for (int g = wave; g < 10; g += 4) {
        const float4* row = (g < 4) ? &v_t4[((size_t)h*4 + g)*NRES]
                                    : &wv_t4[((size_t)h*6 + (g-4))*NRES];
        float px = 0.f, py = 0.f, pz = 0.f, pw = 0.f;
        #pragma unroll
        for (int jj = 0; jj < 8; ++jj) {
            int j = lane + jj*64;
            float a = att[j];
            float4 r = row[j];
            px += a*r.x; py += a*r.y; pz += a*r.z; pw += a*r.w;
        }
        #pragma unroll
        for (int d = 32; d > 0; d >>= 1) {
            px += __shfl_down(px, d);
            py += __shfl_down(py, d);
            pz += __shfl_down(pz, d);
            pw += __shfl_down(pw, d);
        }
        if (lane == 0) {
            if (g < 4) {
                *reinterpret_cast<float4*>(&cat[(size_t)i*CATF + h*16 + g*4]) =
                    make_float4(px, py, pz, pw);
            } else {
                int e = (g-4)*4;
                optl[e] = px; optl[e+1] = py; optl[e+2] = pz; optl[e+3] = pw;
            }
        }
    }
    __syncthreads();

    if (tid < 8) {
        int p = tid;
        float t0 = T[i*16 + 0*4 + 3], t1 = T[i*16 + 1*4 + 3], t2 = T[i*16 + 2*4 + 3];
        float y0 = optl[p*3+0] - t0, y1 = optl[p*3+1] - t1, y2 = optl[p*3+2] - t2;
        float n2 = 0.f;
        #pragma unroll
        for (int x = 0; x < 3; ++x) {
            float w = T[i*16 + 0*4 + x]*y0 + T[i*16 + 1*4 + x]*y1 + T[i*16 + 2*4 + x]*y2;
            cat[(size_t)i*CATF + 192 + x*96 + h*8 + p] = w;
            n2 += w*w;
        }
        cat[(size_t)i*CATF + 480 + h*8 + p] = sqrtf(n2);
    }
}

// ---------------- Kernel 4: pairwise_out = att @ z  -> cat[576:2112] ----------------
__global__ __launch_bounds__(256) void k_pair(
    const float* __restrict__ z, const float* __restrict__ att,
    float* __restrict__ cat)
{
    int i = blockIdx.x, tid = threadIdx.x;
    __shared__ float zl[64*129];
    __shared__ float al[12*64];
    int c = tid & 127, hh = tid >> 7;
    float acc[6] = {0,0,0,0,0,0};
    for (int j0 = 0; j0 < NRES; j0 += 64) {
        __syncthreads();
        for (int idx = tid; idx < 64*128; idx += 256) {
            int j = idx >> 7, cc = idx & 127;
            zl[j*129 + cc] = z[((size_t)i*NRES + j0 + j)*CZ + cc];
        }
        for (int idx = tid; idx < 12*64; idx += 256) {
            int h2 = idx >> 6, jj = idx & 63;
            al[h2*64 + jj] = att[((size_t)h2*NRES + i)*NRES + j0 + jj];
        }
        __syncthreads();
        for (int jj = 0; jj < 64; ++jj) {
            float zv = zl[jj*129 + c];
            #pragma unroll
            for (int m = 0; m < 6; ++m) {
                acc[m] += al[(hh + 2*m)*64 + jj] * zv;
            }
        }
    }
    #pragma unroll
    for (int m = 0; m < 6; ++m) {
        cat[(size_t)i*CATF + 576 + (hh + 2*m)*128 + c] = acc[m];
    }
}

// ---------------- Kernel 5a: split-K Wo GEMM ----------------
__global__ __launch_bounds__(384) void k_wo(
    const float* __restrict__ cat, const float* __restrict__ Wo,
    float* __restrict__ part)
{
    int i0 = blockIdx.x * 8;
    int fs = blockIdx.y;
    int f0 = fs * FCHUNK;
    int tid = threadIdx.x;
    __shared__ float cl[8][FCHUNK];
    for (int idx = tid; idx < 8*(FCHUNK/4); idx += 384) {
        int j = idx / (FCHUNK/4), q = idx % (FCHUNK/4);
        *reinterpret_cast<float4*>(&cl[j][q*4]) =
            *reinterpret_cast<const float4*>(&cat[(size_t)(i0+j)*CATF + f0 + q*4]);
    }
    __syncthreads();
    float acc[8] = {0,0,0,0,0,0,0,0};
    const float* wp = Wo + (size_t)f0*CS + tid;
    #pragma unroll 4
    for (int f = 0; f < FCHUNK; ++f) {
        float w = wp[(size_t)f*CS];
        #pragma unroll
        for (int j = 0; j < 8; ++j) acc[j] = fmaf(w, cl[j][f], acc[j]);
    }
    #pragma unroll
    for (int j = 0; j < 8; ++j)
        part[((size_t)fs*NRES + i0 + j)*CS + tid] = acc[j];
}

// ---------------- Kernel 5b: reduce partials + bias ----------------
__global__ __launch_bounds__(384) void k_red(
    const float* __restrict__ part, const float* __restrict__ bo,
    float* __restrict__ out)
{
    int i = blockIdx.x, o = threadIdx.x;
    float a = bo[o];
    #pragma unroll
    for (int s = 0; s < FSPLIT; ++s)
        a += part[((size_t)s*NRES + i)*CS + o];
    out[(size_t)i*CS + o] = a;
}

// ---------------- launch ----------------
extern "C" void kernel_launch(void* const* d_in, const int* in_sizes, int n_in,
                              void* d_out, int out_size, void* d_ws, size_t ws_size,
                              hipStream_t stream)
{
    const float* s   = (const float*)d_in[0];
    const float* z   = (const float*)d_in[1];
    const float* T   = (const float*)d_in[2];
    const float* Wq  = (const float*)d_in[3];  const float* bq  = (const float*)d_in[4];
    const float* Wk  = (const float*)d_in[5];  const float* bk  = (const float*)d_in[6];
    const float* Wv  = (const float*)d_in[7];  const float* bv  = (const float*)d_in[8];
    const float* Wqp = (const float*)d_in[9];  const float* bqp = (const float*)d_in[10];
    const float* Wkp = (const float*)d_in[11]; const float* bkp = (const float*)d_in[12];
    const float* Wvp = (const float*)d_in[13]; const float* bvp = (const float*)d_in[14];
    const float* Wb  = (const float*)d_in[15]; const float* bb  = (const float*)d_in[16];
    const float* Wo  = (const float*)d_in[17]; const float* bo  = (const float*)d_in[18];
    const float* hw  = (const float*)d_in[19];
    float* out = (float*)d_out;
    float* ws  = (float*)d_ws;

    size_t off = 0;
    float* q_s  = ws + off; off += (size_t)NH*NRES*CC;
    float* k_t  = ws + off; off += (size_t)NH*NRES*CC;
    float* v_t  = ws + off; off += (size_t)NH*NRES*CC;
    float* wq   = ws + off; off += (size_t)NH*NRES*12;
    float* wk_t = ws + off; off += (size_t)NH*NRES*12;
    float* wv_t = ws + off; off += (size_t)NH*NRES*24;
    float* qn   = ws + off; off += (size_t)NH*NRES;
    float* kn   = ws + off; off += (size_t)NH*NRES;
    float* bias = ws + off; off += (size_t)NH*NRES*NRES;
    float* cat  = ws + off; off += (size_t)NRES*CATF;
    float* part = ws + off; off += (size_t)FSPLIT*NRES*CS;
    float* praw = ws + off; off += (size_t)NRES*FTOT;

    k_gemm<<<dim3(NRES/8, 3), dim3(384), 0, stream>>>(
        s, Wq, bq, Wk, bk, Wv, bv, Wqp, bqp, Wkp, bkp, Wvp, bvp, praw);

    k_post<<<dim3(NRES), dim3(256), 0, stream>>>(
        praw, T, q_s, (float4*)k_t, (float4*)v_t, wq, (float4*)wk_t, (float4*)wv_t, qn, kn);

    k_bias<<<dim3(8, NRES), dim3(256), 0, stream>>>(z, Wb, bb, bias);

    k_att<<<dim3(NRES, NH), dim3(256), 0, stream>>>(
        q_s, (const float4*)k_t, wq, (const float4*)wk_t, qn, kn, hw, T, bias,
        (const float4*)v_t, (const float4*)wv_t, cat);

    k_pair<<<dim3(NRES), dim3(256), 0, stream>>>(z, bias, cat);

    k_wo<<<dim3(NRES/8, FSPLIT), dim3(384), 0, stream>>>(cat, Wo, part);

    k_red<<<dim3(NRES), dim3(384), 0, stream>>>(part, bo, out);
}

// Round 9
// 186.405 us; speedup vs baseline: 1.1779x; 1.1779x over previous
//
#include <hip/hip_runtime.h>
#include <hip/hip_bf16.h>
#include <math.h>

// Problem constants
#define NRES 512
#define CS 384
#define CZ 128
#define NH 12
#define CC 16
#define NQP 4
#define NPV 8
#define HC (NH*CC)        // 192
#define FTOT 1152         // 192*3 + 144*2 + 288
#define CATF 2112         // 192 + 288 + 96 + 1536
#define FSPLIT 8
#define FCHUNK 264        // 2112/8
#define W_C 0.23570226039551584f   // sqrt(2/(9*4))
#define W_L 0.5773502691896258f    // sqrt(1/3)

// ---------------- Kernel 1a: all projections as one GEMM ----------------
__global__ __launch_bounds__(384) void k_gemm(
    const float* __restrict__ s,
    const float* __restrict__ Wq, const float* __restrict__ bq,
    const float* __restrict__ Wk, const float* __restrict__ bk,
    const float* __restrict__ Wv, const float* __restrict__ bv,
    const float* __restrict__ Wqp, const float* __restrict__ bqp,
    const float* __restrict__ Wkp, const float* __restrict__ bkp,
    const float* __restrict__ Wvp, const float* __restrict__ bvp,
    float* __restrict__ p_raw)
{
    int r0 = blockIdx.x * 8;
    int f  = blockIdx.y * 384 + threadIdx.x;
    const float* W; const float* bia; int col; int stride;
    if      (f < 192) { W = Wq;  bia = bq;  col = f;       stride = 192; }
    else if (f < 384) { W = Wk;  bia = bk;  col = f - 192; stride = 192; }
    else if (f < 576) { W = Wv;  bia = bv;  col = f - 384; stride = 192; }
    else if (f < 720) { W = Wqp; bia = bqp; col = f - 576; stride = 144; }
    else if (f < 864) { W = Wkp; bia = bkp; col = f - 720; stride = 144; }
    else              { W = Wvp; bia = bvp; col = f - 864; stride = 288; }

    float acc[8];
    float b0 = bia[col];
    #pragma unroll
    for (int j = 0; j < 8; ++j) acc[j] = b0;

    const float* srow = s + (size_t)r0 * CS;
    #pragma unroll 4
    for (int i = 0; i < CS; ++i) {
        float w = W[(size_t)i * stride + col];
        #pragma unroll
        for (int j = 0; j < 8; ++j) acc[j] = fmaf(w, srow[j*CS + i], acc[j]);
    }
    #pragma unroll
    for (int j = 0; j < 8; ++j) p_raw[(size_t)(r0 + j)*FTOT + f] = acc[j];
}

// ---------------- Kernel 1b: warp + transpose layouts ----------------
__global__ __launch_bounds__(256) void k_post(
    const float* __restrict__ p_raw, const float* __restrict__ T,
    float* __restrict__ q_s, float4* __restrict__ k_t4, float4* __restrict__ v_t4,
    float* __restrict__ wq, float4* __restrict__ wk_t4, float4* __restrict__ wv_t4,
    float* __restrict__ qn, float* __restrict__ kn)
{
    int n = blockIdx.x;
    int tid = threadIdx.x;
    __shared__ float pl[FTOT];
    __shared__ float Rl[9], tl[3];
    __shared__ float wq_l[144], wk_l[144], wv_l[288];
    __shared__ float sq_part[48], sk_part[48];

    for (int idx = tid; idx < FTOT/4; idx += 256)
        *reinterpret_cast<float4*>(&pl[idx*4]) =
            *reinterpret_cast<const float4*>(&p_raw[(size_t)n*FTOT + idx*4]);
    if (tid < 9)  Rl[tid] = T[n*16 + (tid/3)*4 + (tid%3)];
    if (tid >= 16 && tid < 19) tl[tid-16] = T[n*16 + (tid-16)*4 + 3];
    __syncthreads();

    if (tid < 48) {
        int h = tid >> 2, p = tid & 3;
        float qy0 = pl[576 + 0*48 + h*4 + p], qy1 = pl[576 + 1*48 + h*4 + p], qy2 = pl[576 + 2*48 + h*4 + p];
        float ky0 = pl[720 + 0*48 + h*4 + p], ky1 = pl[720 + 1*48 + h*4 + p], ky2 = pl[720 + 2*48 + h*4 + p];
        float qs2 = 0.f, ks2 = 0.f;
        #pragma unroll
        for (int x = 0; x < 3; ++x) {
            float wqv = Rl[x*3+0]*qy0 + Rl[x*3+1]*qy1 + Rl[x*3+2]*qy2 + tl[x];
            float wkv = Rl[x*3+0]*ky0 + Rl[x*3+1]*ky1 + Rl[x*3+2]*ky2 + tl[x];
            wq_l[h*12 + p*3 + x] = wqv;
            wk_l[h*12 + p*3 + x] = wkv;
            qs2 += wqv*wqv; ks2 += wkv*wkv;
        }
        sq_part[tid] = qs2; sk_part[tid] = ks2;
    } else if (tid >= 64 && tid < 160) {
        int u = tid - 64; int h = u >> 3, p = u & 7;
        float y0 = pl[864 + 0*96 + h*8 + p], y1 = pl[864 + 1*96 + h*8 + p], y2 = pl[864 + 2*96 + h*8 + p];
        #pragma unroll
        for (int x = 0; x < 3; ++x) {
            wv_l[h*24 + p*3 + x] = Rl[x*3+0]*y0 + Rl[x*3+1]*y1 + Rl[x*3+2]*y2 + tl[x];
        }
    }
    __syncthreads();

    if (tid < 48) {
        int h = tid >> 2, c4 = tid & 3;
        float4 qv = *reinterpret_cast<const float4*>(&pl[h*16 + c4*4]);
        qv.x *= 0.25f; qv.y *= 0.25f; qv.z *= 0.25f; qv.w *= 0.25f;
        float4 kv = *reinterpret_cast<const float4*>(&pl[192 + h*16 + c4*4]);
        float4 vv = *reinterpret_cast<const float4*>(&pl[384 + h*16 + c4*4]);
        *reinterpret_cast<float4*>(&q_s[((size_t)h*NRES + n)*16 + c4*4]) = qv;
        k_t4[((size_t)h*4 + c4)*NRES + n] = kv;
        v_t4[((size_t)h*4 + c4)*NRES + n] = vv;
    } else if (tid >= 64 && tid < 100) {
        int u = tid - 64; int h = u / 3, e4 = u % 3;
        float4 kv = *reinterpret_cast<const float4*>(&wk_l[h*12 + e4*4]);
        wk_t4[((size_t)h*3 + e4)*NRES + n] = kv;
    } else if (tid >= 104 && tid < 140) {
        int u = tid - 104; int h = u / 3, e4 = u % 3;
        float4 qv = *reinterpret_cast<const float4*>(&wq_l[h*12 + e4*4]);
        *reinterpret_cast<float4*>(&wq[((size_t)h*NRES + n)*12 + e4*4]) = qv;
    } else if (tid >= 160 && tid < 232) {
        int u = tid - 160; int h = u / 6, e4 = u % 6;
        float4 vv = *reinterpret_cast<const float4*>(&wv_l[h*24 + e4*4]);
        wv_t4[((size_t)h*6 + e4)*NRES + n] = vv;
    } else if (tid >= 232 && tid < 244) {
        int h = tid - 232;
        qn[(size_t)h*NRES + n] = sq_part[h*4] + sq_part[h*4+1] + sq_part[h*4+2] + sq_part[h*4+3];
        kn[(size_t)h*NRES + n] = sk_part[h*4] + sk_part[h*4+1] + sk_part[h*4+2] + sk_part[h*4+3];
    }
}

// ---------------- Kernel 2: bias = z @ Wb + bb  -> [H][N][N] ----------------
// Coalesced global->LDS staging (z element read from LDS exactly ONCE);
// Wb reads wave-uniform -> broadcast (c4 depends only on wave id);
// 4 threads/row split across the 4 waves; partial reduce via LDS.
__global__ __launch_bounds__(256) void k_bias(
    const float* __restrict__ z, const float* __restrict__ Wb,
    const float* __restrict__ bb, float* __restrict__ bias)
{
    int j0 = blockIdx.x * 64, i = blockIdx.y;
    int tid = threadIdx.x;
    int r = tid & 63, p = tid >> 6;   // p = wave index (0..3)
    __shared__ float zl[64*132];      // 33KB, stride 132 (16B-aligned)
    __shared__ float wbl[12*128];     // [h][c]
    __shared__ float partial[4][12][64];
    __shared__ float bbl[12];

    for (int idx = tid; idx < 1536; idx += 256) {
        int h = idx >> 7, c = idx & 127;
        wbl[idx] = Wb[c*12 + h];      // consecutive idx -> consecutive LDS
    }
    if (tid < 12) bbl[tid] = bb[tid];
    const float4* zsrc = reinterpret_cast<const float4*>(z + ((size_t)i*NRES + j0)*CZ);
    #pragma unroll
    for (int it = 0; it < 8; ++it) {
        int idx = it*256 + tid;       // contiguous 4KB per instruction
        int j = idx >> 5, c4 = idx & 31;
        *reinterpret_cast<float4*>(&zl[j*132 + c4*4]) = zsrc[idx];
    }
    __syncthreads();

    float acc[12] = {0,0,0,0,0,0,0,0,0,0,0,0};
    #pragma unroll 2
    for (int it = 0; it < 8; ++it) {
        int c4 = p*8 + it;            // wave-uniform
        float4 zv = *reinterpret_cast<const float4*>(&zl[r*132 + c4*4]);
        #pragma unroll
        for (int h = 0; h < 12; ++h) {
            float4 wv = *reinterpret_cast<const float4*>(&wbl[h*128 + c4*4]);
            acc[h] = fmaf(zv.x, wv.x, fmaf(zv.y, wv.y, fmaf(zv.z, wv.z, fmaf(zv.w, wv.w, acc[h]))));
        }
    }
    #pragma unroll
    for (int h = 0; h < 12; ++h) partial[p][h][r] = acc[h];
    __syncthreads();

    #pragma unroll
    for (int u = 0; u < 3; ++u) {
        int idx = u*256 + tid;
        int h = idx >> 6, rr = idx & 63;
        float v = partial[0][h][rr] + partial[1][h][rr]
                + partial[2][h][rr] + partial[3][h][rr] + bbl[h];
        bias[((size_t)h*NRES + i)*NRES + j0 + rr] = v;
    }
}

// ------- Kernel 3: att softmax (in-place over bias) + v_out + o_pt transform -> cat -------
__global__ __launch_bounds__(256) void k_att(
    const float* __restrict__ q_s, const float4* __restrict__ k_t4,
    const float* __restrict__ wq, const float4* __restrict__ wk_t4,
    const float* __restrict__ qn, const float* __restrict__ kn,
    const float* __restrict__ hw, const float* __restrict__ T,
    float* __restrict__ bias,       // in: bias, out: att
    const float4* __restrict__ v_t4, const float4* __restrict__ wv_t4,
    float* __restrict__ cat)
{
    int i = blockIdx.x, h = blockIdx.y;
    int tid = threadIdx.x;
    __shared__ float ql[16], wql[12];
    __shared__ float att[NRES];
    __shared__ float red[8];
    __shared__ float optl[24];
    __shared__ float sG, sQn;

    if (tid < 16) ql[tid] = q_s[((size_t)h*NRES + i)*16 + tid];
    else if (tid < 28) wql[tid-16] = wq[((size_t)h*NRES + i)*12 + (tid-16)];
    if (tid == 0) {
        sQn = qn[(size_t)h*NRES + i];
        float x = hw[h];
        float sp = (x > 20.f) ? x : log1pf(expf(x));
        sG = sp * W_C * 0.5f;
    }
    __syncthreads();
    float qn_i = sQn, gam = sG;

    float lg[2];
    #pragma unroll
    for (int m = 0; m < 2; ++m) {
        int j = tid + m*256;
        float qk = 0.f;
        #pragma unroll
        for (int c4 = 0; c4 < 4; ++c4) {
            float4 kv = k_t4[((size_t)h*4 + c4)*NRES + j];
            qk += ql[c4*4+0]*kv.x + ql[c4*4+1]*kv.y + ql[c4*4+2]*kv.z + ql[c4*4+3]*kv.w;
        }
        float dd = 0.f;
        #pragma unroll
        for (int e4 = 0; e4 < 3; ++e4) {
            float4 kv = wk_t4[((size_t)h*3 + e4)*NRES + j];
            dd += wql[e4*4+0]*kv.x + wql[e4*4+1]*kv.y + wql[e4*4+2]*kv.z + wql[e4*4+3]*kv.w;
        }
        float d2 = qn_i + kn[(size_t)h*NRES + j] - 2.f*dd;
        lg[m] = W_L * (qk + bias[((size_t)h*NRES + i)*NRES + j] - gam*d2);
    }

    int wave = tid >> 6, lane = tid & 63;
    float mx = fmaxf(lg[0], lg[1]);
    #pragma unroll
    for (int d = 32; d > 0; d >>= 1) mx = fmaxf(mx, __shfl_xor(mx, d));
    if (lane == 0) red[wave] = mx;
    __syncthreads();
    mx = fmaxf(fmaxf(red[0], red[1]), fmaxf(red[2], red[3]));
    float e0 = __expf(lg[0]-mx), e1 = __expf(lg[1]-mx);
    float sm = e0 + e1;
    #pragma unroll
    for (int d = 32; d > 0; d >>= 1) sm += __shfl_xor(sm, d);
    if (lane == 0) red[4+wave] = sm;
    __syncthreads();
    float inv = 1.f / (red[4]+red[5]+red[6]+red[7]);
    float a0 = e0*inv, a1 = e1*inv;
    att[tid] = a0; att[tid+256] = a1;
    bias[((size_t)h*NRES + i)*NRES + tid]       = a0;
    bias[((size_t)h*NRES + i)*NRES + tid + 256] = a1;
    __syncthreads();

    for (int g = wave; g < 10; g += 4) {
        const float4* row = (g < 4) ? &v_t4[((size_t)h*4 + g)*NRES]
                                    : &wv_t4[((size_t)h*6 + (g-4))*NRES];
        float px = 0.f, py = 0.f, pz = 0.f, pw = 0.f;
        #pragma unroll
        for (int jj = 0; jj < 8; ++jj) {
            int j = lane + jj*64;
            float a = att[j];
            float4 r = row[j];
            px += a*r.x; py += a*r.y; pz += a*r.z; pw += a*r.w;
        }
        #pragma unroll
        for (int d = 32; d > 0; d >>= 1) {
            px += __shfl_down(px, d);
            py += __shfl_down(py, d);
            pz += __shfl_down(pz, d);
            pw += __shfl_down(pw, d);
        }
        if (lane == 0) {
            if (g < 4) {
                *reinterpret_cast<float4*>(&cat[(size_t)i*CATF + h*16 + g*4]) =
                    make_float4(px, py, pz, pw);
            } else {
                int e = (g-4)*4;
                optl[e] = px; optl[e+1] = py; optl[e+2] = pz; optl[e+3] = pw;
            }
        }
    }
    __syncthreads();

    if (tid < 8) {
        int p = tid;
        float t0 = T[i*16 + 0*4 + 3], t1 = T[i*16 + 1*4 + 3], t2 = T[i*16 + 2*4 + 3];
        float y0 = optl[p*3+0] - t0, y1 = optl[p*3+1] - t1, y2 = optl[p*3+2] - t2;
        float n2 = 0.f;
        #pragma unroll
        for (int x = 0; x < 3; ++x) {
            float w = T[i*16 + 0*4 + x]*y0 + T[i*16 + 1*4 + x]*y1 + T[i*16 + 2*4 + x]*y2;
            cat[(size_t)i*CATF + 192 + x*96 + h*8 + p] = w;
            n2 += w*w;
        }
        cat[(size_t)i*CATF + 480 + h*8 + p] = sqrtf(n2);
    }
}

// ---------------- Kernel 4: pairwise_out = att @ z  -> cat[576:2112] ----------------
__global__ __launch_bounds__(256) void k_pair(
    const float* __restrict__ z, const float* __restrict__ att,
    float* __restrict__ cat)
{
    int i = blockIdx.x, tid = threadIdx.x;
    __shared__ float zl[64*129];
    __shared__ float al[12*64];
    int c = tid & 127, hh = tid >> 7;
    float acc[6] = {0,0,0,0,0,0};
    for (int j0 = 0; j0 < NRES; j0 += 64) {
        __syncthreads();
        for (int idx = tid; idx < 64*128; idx += 256) {
            int j = idx >> 7, cc = idx & 127;
            zl[j*129 + cc] = z[((size_t)i*NRES + j0 + j)*CZ + cc];
        }
        for (int idx = tid; idx < 12*64; idx += 256) {
            int h2 = idx >> 6, jj = idx & 63;
            al[h2*64 + jj] = att[((size_t)h2*NRES + i)*NRES + j0 + jj];
        }
        __syncthreads();
        for (int jj = 0; jj < 64; ++jj) {
            float zv = zl[jj*129 + c];
            #pragma unroll
            for (int m = 0; m < 6; ++m) {
                acc[m] += al[(hh + 2*m)*64 + jj] * zv;
            }
        }
    }
    #pragma unroll
    for (int m = 0; m < 6; ++m) {
        cat[(size_t)i*CATF + 576 + (hh + 2*m)*128 + c] = acc[m];
    }
}

// ---------------- Kernel 5a: split-K Wo GEMM ----------------
__global__ __launch_bounds__(384) void k_wo(
    const float* __restrict__ cat, const float* __restrict__ Wo,
    float* __restrict__ part)
{
    int i0 = blockIdx.x * 8;
    int fs = blockIdx.y;
    int f0 = fs * FCHUNK;
    int tid = threadIdx.x;
    __shared__ float cl[8][FCHUNK];
    for (int idx = tid; idx < 8*(FCHUNK/4); idx += 384) {
        int j = idx / (FCHUNK/4), q = idx % (FCHUNK/4);
        *reinterpret_cast<float4*>(&cl[j][q*4]) =
            *reinterpret_cast<const float4*>(&cat[(size_t)(i0+j)*CATF + f0 + q*4]);
    }
    __syncthreads();
    float acc[8] = {0,0,0,0,0,0,0,0};
    const float* wp = Wo + (size_t)f0*CS + tid;
    #pragma unroll 4
    for (int f = 0; f < FCHUNK; ++f) {
        float w = wp[(size_t)f*CS];
        #pragma unroll
        for (int j = 0; j < 8; ++j) acc[j] = fmaf(w, cl[j][f], acc[j]);
    }
    #pragma unroll
    for (int j = 0; j < 8; ++j)
        part[((size_t)fs*NRES + i0 + j)*CS + tid] = acc[j];
}

// ---------------- Kernel 5b: reduce partials + bias ----------------
__global__ __launch_bounds__(384) void k_red(
    const float* __restrict__ part, const float* __restrict__ bo,
    float* __restrict__ out)
{
    int i = blockIdx.x, o = threadIdx.x;
    float a = bo[o];
    #pragma unroll
    for (int s = 0; s < FSPLIT; ++s)
        a += part[((size_t)s*NRES + i)*CS + o];
    out[(size_t)i*CS + o] = a;
}

// ---------------- launch ----------------
extern "C" void kernel_launch(void* const* d_in, const int* in_sizes, int n_in,
                              void* d_out, int out_size, void* d_ws, size_t ws_size,
                              hipStream_t stream)
{
    const float* s   = (const float*)d_in[0];
    const float* z   = (const float*)d_in[1];
    const float* T   = (const float*)d_in[2];
    const float* Wq  = (const float*)d_in[3];  const float* bq  = (const float*)d_in[4];
    const float* Wk  = (const float*)d_in[5];  const float* bk  = (const float*)d_in[6];
    const float* Wv  = (const float*)d_in[7];  const float* bv  = (const float*)d_in[8];
    const float* Wqp = (const float*)d_in[9];  const float* bqp = (const float*)d_in[10];
    const float* Wkp = (const float*)d_in[11]; const float* bkp = (const float*)d_in[12];
    const float* Wvp = (const float*)d_in[13]; const float* bvp = (const float*)d_in[14];
    const float* Wb  = (const float*)d_in[15]; const float* bb  = (const float*)d_in[16];
    const float* Wo  = (const float*)d_in[17]; const float* bo  = (const float*)d_in[18];
    const float* hw  = (const float*)d_in[19];
    float* out = (float*)d_out;
    float* ws  = (float*)d_ws;

    size_t off = 0;
    float* q_s  = ws + off; off += (size_t)NH*NRES*CC;
    float* k_t  = ws + off; off += (size_t)NH*NRES*CC;
    float* v_t  = ws + off; off += (size_t)NH*NRES*CC;
    float* wq   = ws + off; off += (size_t)NH*NRES*12;
    float* wk_t = ws + off; off += (size_t)NH*NRES*12;
    float* wv_t = ws + off; off += (size_t)NH*NRES*24;
    float* qn   = ws + off; off += (size_t)NH*NRES;
    float* kn   = ws + off; off += (size_t)NH*NRES;
    float* bias = ws + off; off += (size_t)NH*NRES*NRES;
    float* cat  = ws + off; off += (size_t)NRES*CATF;
    float* part = ws + off; off += (size_t)FSPLIT*NRES*CS;
    float* praw = ws + off; off += (size_t)NRES*FTOT;

    k_gemm<<<dim3(NRES/8, 3), dim3(384), 0, stream>>>(
        s, Wq, bq, Wk, bk, Wv, bv, Wqp, bqp, Wkp, bkp, Wvp, bvp, praw);

    k_post<<<dim3(NRES), dim3(256), 0, stream>>>(
        praw, T, q_s, (float4*)k_t, (float4*)v_t, wq, (float4*)wk_t, (float4*)wv_t, qn, kn);

    k_bias<<<dim3(8, NRES), dim3(256), 0, stream>>>(z, Wb, bb, bias);

    k_att<<<dim3(NRES, NH), dim3(256), 0, stream>>>(
        q_s, (const float4*)k_t, wq, (const float4*)wk_t, qn, kn, hw, T, bias,
        (const float4*)v_t, (const float4*)wv_t, cat);

    k_pair<<<dim3(NRES), dim3(256), 0, stream>>>(z, bias, cat);

    k_wo<<<dim3(NRES/8, FSPLIT), dim3(384), 0, stream>>>(cat, Wo, part);

    k_red<<<dim3(NRES), dim3(384), 0, stream>>>(part, bo, out);
}